// Round 23
// baseline (453.098 us; speedup 1.0000x reference)
//
#include <hip/hip_runtime.h>

// Problem dims
#define B_    8
#define N_    1024
#define DIN   512
#define H_    8
#define DH    64
#define DQKV  6144   // 2*DQ + 2*DQ + DV = 512+512+512+512+4096
#define DEXP  2048
#define DTIME 256

typedef __attribute__((ext_vector_type(8))) short s16x8;   // 8 bf16 (MFMA A/B frag)
typedef __attribute__((ext_vector_type(4))) short s16x4;
typedef __attribute__((ext_vector_type(4))) float f32x4;   // MFMA C/D frag

__device__ __forceinline__ unsigned short f2bf(float f) {
  unsigned int u = __float_as_uint(f);
  u = (u + 0x7fffu + ((u >> 16) & 1u)) >> 16;   // RNE
  return (unsigned short)u;
}

__device__ __forceinline__ void gload_lds16(const unsigned short* g, unsigned short* l) {
  __builtin_amdgcn_global_load_lds(
      (const __attribute__((address_space(1))) unsigned int*)(g),
      (__attribute__((address_space(3))) unsigned int*)(l), 16, 0, 0);
}

#define WAITV(n) do { asm volatile("s_waitcnt vmcnt(" #n ")" ::: "memory"); \
                      __builtin_amdgcn_sched_barrier(0); } while (0)
#define WAITL0() do { asm volatile("s_waitcnt lgkmcnt(0)" ::: "memory"); \
                      __builtin_amdgcn_sched_barrier(0); } while (0)

// ---------------- prep mega-kernel: 4x weight-transpose + time MLP + LN1 --------
// blocks [0,7168): 32x32 f32->bf16T tiles; [7168,7176): time MLP; rest: LN rows.
__global__ __launch_bounds__(256) void prep_k(
    const float* __restrict__ Wqkv, unsigned short* __restrict__ WqkvT,
    const float* __restrict__ Wm,   unsigned short* __restrict__ WmT,
    const float* __restrict__ Wf1,  unsigned short* __restrict__ Wf1T,
    const float* __restrict__ Wf2,  unsigned short* __restrict__ Wf2T,
    const float* __restrict__ t,    const float* __restrict__ Wt1,
    const float* __restrict__ bt1,  const float* __restrict__ Wt2,
    const float* __restrict__ bt2,  float* __restrict__ tp,
    const float* __restrict__ x,    const float* __restrict__ ln1g,
    const float* __restrict__ ln1b, unsigned short* __restrict__ xn)
{
  __shared__ float tile[32][33];
  __shared__ float tl[256], hl[256];
  __shared__ float red[8];
  int bid = blockIdx.x;
  int tid = threadIdx.x;
  if (bid < 7168) {
    const float* in; unsigned short* out; int R, C, gx, gy;
    if (bid < 3072)      { in = Wqkv; out = WqkvT; R = 512;  C = 6144; gx = bid % 192;          gy = bid / 192; }
    else if (bid < 5120) { int b2 = bid - 3072; in = Wm;  out = WmT;  R = 4096; C = 512;  gx = b2 % 16; gy = b2 / 16; }
    else if (bid < 6144) { int b3 = bid - 5120; in = Wf1; out = Wf1T; R = 512;  C = 2048; gx = b3 % 64; gy = b3 / 64; }
    else                 { int b4 = bid - 6144; in = Wf2; out = Wf2T; R = 2048; C = 512;  gx = b4 % 16; gy = b4 / 16; }
    int tx = tid & 31, ty = tid >> 5;
    int c0 = gx * 32, r0 = gy * 32;
    #pragma unroll
    for (int k = 0; k < 4; ++k)
      tile[ty + k * 8][tx] = in[(size_t)(r0 + ty + k * 8) * C + c0 + tx];
    __syncthreads();
    #pragma unroll
    for (int k = 0; k < 4; ++k)
      out[(size_t)(c0 + ty + k * 8) * R + r0 + tx] = f2bf(tile[tx][ty + k * 8]);
    return;
  }
  if (bid < 7176) {
    int b = bid - 7168;
    tl[tid] = t[(size_t)b * 256 + tid];
    __syncthreads();
    float a = bt1[tid];
    for (int k = 0; k < 256; ++k) a += tl[k] * Wt1[(size_t)k * 256 + tid];
    hl[tid] = a / (1.0f + __expf(-a));
    __syncthreads();
    for (int j = tid; j < 512; j += 256) {
      float a2 = bt2[j];
      for (int k = 0; k < 256; ++k) a2 += hl[k] * Wt2[(size_t)k * 512 + j];
      tp[(size_t)b * 512 + j] = a2;
    }
    return;
  }
  int row = bid - 7176;
  const float* xr = x + (size_t)row * DIN;
  float v0 = xr[tid], v1 = xr[tid + 256];
  float s = v0 + v1, sq = v0 * v0 + v1 * v1;
  #pragma unroll
  for (int m = 1; m < 64; m <<= 1) { s += __shfl_xor(s, m, 64); sq += __shfl_xor(sq, m, 64); }
  int w = tid >> 6;
  if ((tid & 63) == 0) { red[w] = s; red[4 + w] = sq; }
  __syncthreads();
  s  = red[0] + red[1] + red[2] + red[3];
  sq = red[4] + red[5] + red[6] + red[7];
  float mean = s * (1.0f / DIN);
  float var  = sq * (1.0f / DIN) - mean * mean;
  float rs = rsqrtf(var + 1e-5f);
  unsigned short* orow = xn + (size_t)row * DIN;
  orow[tid]       = f2bf((v0 - mean) * rs * ln1g[tid]       + ln1b[tid]);
  orow[tid + 256] = f2bf((v1 - mean) * rs * ln1g[tid + 256] + ln1b[tid + 256]);
}

// ---------------- LayerNorm (D=512), additive per-batch row, bf16 out -----------
__global__ __launch_bounds__(256) void ln_k(
    const float* __restrict__ x, const float* __restrict__ add,
    const float* __restrict__ g, const float* __restrict__ bb,
    unsigned short* __restrict__ out)
{
  int row = blockIdx.x;
  int tid = threadIdx.x;
  const float* xr = x + (size_t)row * DIN;
  float v0 = xr[tid], v1 = xr[tid + 256];
  if (add) {
    const float* ar = add + (size_t)(row >> 10) * DIN;   // row/1024 = batch idx
    v0 += ar[tid]; v1 += ar[tid + 256];
  }
  float s = v0 + v1, sq = v0 * v0 + v1 * v1;
  #pragma unroll
  for (int m = 1; m < 64; m <<= 1) { s += __shfl_xor(s, m, 64); sq += __shfl_xor(sq, m, 64); }
  __shared__ float red[8];
  int w = tid >> 6;
  if ((tid & 63) == 0) { red[w] = s; red[4 + w] = sq; }
  __syncthreads();
  s  = red[0] + red[1] + red[2] + red[3];
  sq = red[4] + red[5] + red[6] + red[7];
  float mean = s * (1.0f / DIN);
  float var  = sq * (1.0f / DIN) - mean * mean;
  float rs = rsqrtf(var + 1e-5f);
  unsigned short* orow = out + (size_t)row * DIN;
  orow[tid]       = f2bf((v0 - mean) * rs * g[tid]       + bb[tid]);
  orow[tid + 256] = f2bf((v1 - mean) * rs * g[tid + 256] + bb[tid + 256]);
}

#define GSWZ(Lb, base, row, colu) \
  (*(const s16x8*)&(Lb)[(base) + (row) * 64 + (((colu) ^ (((row) & 7) * 8)))])

// ---------------- bf16 MFMA GEMM: C = epi(A @ Bt^T + bias [+res]) ---------------
// 128x128 tile, BK=64, 4 waves; double-buffered LDS, 1 barrier/k-step.
template<int EPI>
__global__ __launch_bounds__(256) void gemm_bt(
    const unsigned short* __restrict__ A, int lda,
    const unsigned short* __restrict__ Bt,
    const float* __restrict__ bias, const float* __restrict__ res,
    void* __restrict__ C, int ldc, int N, int K,
    unsigned short* __restrict__ vtout)
{
  __shared__ __attribute__((aligned(16))) unsigned short As[2 * 8192]; // 128x64 x2
  __shared__ __attribute__((aligned(16))) unsigned short Bs[2 * 8192];
  int tid = threadIdx.x;
  int m0 = blockIdx.y * 128, n0 = blockIdx.x * 128;
  int lane = tid & 63, wid = tid >> 6;
  int wr = wid >> 1, wc = wid & 1;
  int lr = lane & 15, lg = lane >> 4, lk = lg * 8;
  f32x4 zero = {0.f, 0.f, 0.f, 0.f};
  f32x4 acc[4][4];
  #pragma unroll
  for (int i = 0; i < 4; ++i)
    #pragma unroll
    for (int j = 0; j < 4; ++j) acc[i][j] = zero;
  int srow = wid * 8 + (lane >> 3);
  int scol = ((lane & 7) ^ (lane >> 3)) * 8;
  const unsigned short* gA = A  + (size_t)(m0 + srow) * lda + scol;
  const unsigned short* gB = Bt + (size_t)(n0 + srow) * K + scol;
  int nk = K >> 6;
  #pragma unroll
  for (int i = 0; i < 4; ++i) {
    gload_lds16(gA + (size_t)(i * 32) * lda, As + (i * 32 + wid * 8) * 64);
    gload_lds16(gB + (size_t)(i * 32) * K,   Bs + (i * 32 + wid * 8) * 64);
  }
  __syncthreads();
  for (int kq = 0; kq < nk; ++kq) {
    int cur = (kq & 1) * 8192;
    if (kq + 1 < nk) {
      int nxt = ((kq + 1) & 1) * 8192;
      int kt = (kq + 1) * 64;
      #pragma unroll
      for (int i = 0; i < 4; ++i) {
        gload_lds16(gA + (size_t)(i * 32) * lda + kt, As + nxt + (i * 32 + wid * 8) * 64);
        gload_lds16(gB + (size_t)(i * 32) * K   + kt, Bs + nxt + (i * 32 + wid * 8) * 64);
      }
    }
    s16x8 af[4][2], bf[4][2];
    #pragma unroll
    for (int mf = 0; mf < 4; ++mf) {
      int row = wr * 64 + mf * 16 + lr;
      af[mf][0] = GSWZ(As, cur, row, lk);
      af[mf][1] = GSWZ(As, cur, row, 32 + lk);
    }
    #pragma unroll
    for (int nf = 0; nf < 4; ++nf) {
      int row = wc * 64 + nf * 16 + lr;
      bf[nf][0] = GSWZ(Bs, cur, row, lk);
      bf[nf][1] = GSWZ(Bs, cur, row, 32 + lk);
    }
    #pragma unroll
    for (int mf = 0; mf < 4; ++mf)
      #pragma unroll
      for (int nf = 0; nf < 4; ++nf) {
        acc[mf][nf] = __builtin_amdgcn_mfma_f32_16x16x32_bf16(af[mf][0], bf[nf][0], acc[mf][nf], 0, 0, 0);
        acc[mf][nf] = __builtin_amdgcn_mfma_f32_16x16x32_bf16(af[mf][1], bf[nf][1], acc[mf][nf], 0, 0, 0);
      }
    __syncthreads();
  }
  if (EPI == 3 && n0 >= 2048) {
    #pragma unroll
    for (int mf = 0; mf < 4; ++mf) {
      int row = m0 + wr * 64 + mf * 16 + lg * 4;
      int bb = row >> 10, nn = row & 1023;
      #pragma unroll
      for (int nf = 0; nf < 4; ++nf) {
        int col = n0 + wc * 64 + nf * 16 + lr;
        float bcol = bias[col];
        int hc = col - 2048;
        int hh = hc >> 9, cc = hc & 511;
        unsigned short pk[4];
        #pragma unroll
        for (int r = 0; r < 4; ++r) pk[r] = f2bf(acc[mf][nf][r] + bcol);
        *(s16x4*)(vtout + ((size_t)((bb * 8 + hh) * 512 + cc)) * 1024 + nn) = *(const s16x4*)pk;
      }
    }
    return;
  }
  #pragma unroll
  for (int mf = 0; mf < 4; ++mf)
    #pragma unroll
    for (int nf = 0; nf < 4; ++nf) {
      int col = n0 + wc * 64 + nf * 16 + lr;
      float bcol = bias[col];
      #pragma unroll
      for (int r = 0; r < 4; ++r) {
        int row = m0 + wr * 64 + mf * 16 + lg * 4 + r;
        float v = acc[mf][nf][r] + bcol;
        if (EPI == 1) v = v / (1.0f + __expf(-v));            // swish
        if (EPI == 2) {
          v += res[(size_t)row * N + col];
          ((float*)C)[(size_t)row * ldc + col] = v;
        } else {
          ((unsigned short*)C)[(size_t)row * ldc + col] = f2bf(v);
        }
      }
    }
}

// ---------------- 64x128 GEMM (bias + f32 residual), 3-stage counted-vmcnt ------
// proj/ff2 (K-heavy, N=512). TRIPLE-buffered LDS, depth-2 staging: stage(kq+2)
// issued at kq stays IN FLIGHT across the barrier (T4); WAITV(6) drains only
// stage(kq+1). 72KB LDS -> 2 blocks/CU (traded vs r21's 3; pipeline compensates).
__global__ __launch_bounds__(256) void gemm_bt64(
    const unsigned short* __restrict__ A, int lda,
    const unsigned short* __restrict__ Bt,
    const float* __restrict__ bias, const float* __restrict__ res,
    float* __restrict__ C, int ldc, int N, int K)
{
  __shared__ __attribute__((aligned(16))) unsigned short As[3 * 4096]; // 64x64 x3
  __shared__ __attribute__((aligned(16))) unsigned short Bs[3 * 8192]; // 128x64 x3
  int tid = threadIdx.x;
  int m0 = blockIdx.y * 64, n0 = blockIdx.x * 128;
  int lane = tid & 63, wid = tid >> 6;
  int lr = lane & 15, lg = lane >> 4, lk = lg * 8;
  f32x4 zero = {0.f, 0.f, 0.f, 0.f};
  f32x4 acc[4][2];
  #pragma unroll
  for (int i = 0; i < 4; ++i) { acc[i][0] = zero; acc[i][1] = zero; }
  int srow = wid * 8 + (lane >> 3);          // 0..31
  int scol = ((lane & 7) ^ (lane >> 3)) * 8;
  const unsigned short* gA = A  + (size_t)(m0 + srow) * lda + scol;
  const unsigned short* gB = Bt + (size_t)(n0 + srow) * K + scol;
  int nk = K >> 6;
  // 6 gloads per thread per stage (2 A + 4 B)
  auto stage = [&](int slot, int kt) {
    unsigned short* as = As + slot * 4096;
    unsigned short* bs = Bs + slot * 8192;
    gload_lds16(gA + kt,                       as + (wid * 8) * 64);
    gload_lds16(gA + (size_t)32 * lda + kt,    as + (32 + wid * 8) * 64);
    gload_lds16(gB + kt,                       bs + (wid * 8) * 64);
    gload_lds16(gB + (size_t)32 * K + kt,      bs + (32 + wid * 8) * 64);
    gload_lds16(gB + (size_t)64 * K + kt,      bs + (64 + wid * 8) * 64);
    gload_lds16(gB + (size_t)96 * K + kt,      bs + (96 + wid * 8) * 64);
  };
  // prologue: stage tiles 0,1; drain only tile 0 (tile 1 stays in flight)
  stage(0, 0);
  stage(1, 64);
  WAITV(6);
  __builtin_amdgcn_s_barrier();
  int cur = 0;
  for (int kq = 0; kq < nk; ++kq) {
    int stg = cur + 2; if (stg >= 3) stg -= 3;
    if (kq + 2 < nk) stage(stg, (kq + 2) * 64);
    int baseA = cur * 4096, baseB = cur * 8192;
    s16x8 af[4][2], bf[2][2];
    #pragma unroll
    for (int mf = 0; mf < 4; ++mf) {
      int row = mf * 16 + lr;
      af[mf][0] = GSWZ(As, baseA, row, lk);
      af[mf][1] = GSWZ(As, baseA, row, 32 + lk);
    }
    #pragma unroll
    for (int nf = 0; nf < 2; ++nf) {
      int row = wid * 32 + nf * 16 + lr;
      bf[nf][0] = GSWZ(Bs, baseB, row, lk);
      bf[nf][1] = GSWZ(Bs, baseB, row, 32 + lk);
    }
    #pragma unroll
    for (int mf = 0; mf < 4; ++mf)
      #pragma unroll
      for (int nf = 0; nf < 2; ++nf) {
        acc[mf][nf] = __builtin_amdgcn_mfma_f32_16x16x32_bf16(af[mf][0], bf[nf][0], acc[mf][nf], 0, 0, 0);
        acc[mf][nf] = __builtin_amdgcn_mfma_f32_16x16x32_bf16(af[mf][1], bf[nf][1], acc[mf][nf], 0, 0, 0);
      }
    if (kq + 1 < nk) {
      if (kq + 2 < nk) { WAITV(6); }   // drain stage(kq+1); stage(kq+2) in flight
      else             { WAITV(0); }   // tail: drain last stage
      WAITL0();                        // this iter's ds_reads retired
      __builtin_amdgcn_s_barrier();
    }
    cur = cur + 1; if (cur >= 3) cur = 0;
  }
  #pragma unroll
  for (int mf = 0; mf < 4; ++mf)
    #pragma unroll
    for (int nf = 0; nf < 2; ++nf) {
      int col = n0 + wid * 32 + nf * 16 + lr;
      float bcol = bias[col];
      #pragma unroll
      for (int r = 0; r < 4; ++r) {
        int row = m0 + mf * 16 + lg * 4 + r;
        C[(size_t)row * ldc + col] = acc[mf][nf][r] + bcol + res[(size_t)row * N + col];
      }
    }
}

// ---------------- fused differential attention, QBLK=128 (r20-exact) ------------
__global__ __launch_bounds__(512) void attn_k(
    const unsigned short* __restrict__ qkv, const unsigned short* __restrict__ vt,
    const float* __restrict__ lamp, unsigned short* __restrict__ aout /* = qkv+2048 */)
{
  const float scale = 0.125f;
  __shared__ __attribute__((aligned(16))) unsigned short KP[33792];
  int w0 = blockIdx.x;
  int bx = (w0 & 7) * 64 + (w0 >> 3);         // 512 blocks, bijective XCD swizzle
  int bh = bx >> 3, qt = bx & 7;
  int b = bh >> 3, h = bh & 7;
  int tid = threadIdx.x;
  int lane = tid & 63, w = tid >> 6;
  int lr = lane & 15, lg = lane >> 4, lk = lg * 8;
  int qc1 = h * 64, qc2 = 512 + h * 64, kc1 = 1024 + h * 64, kc2 = 1536 + h * 64;
  f32x4 zero = {0.f, 0.f, 0.f, 0.f};
  const unsigned short* kvbase = qkv + (size_t)(b * N_) * DQKV;

  int srw = lane >> 4;                        // 0..3
  int ci0 = (lane & 15) ^ srw;
  int ci1 = (lane & 15) ^ (4 + srw);
  int scol0 = (ci0 < 8) ? (kc1 + ci0 * 8) : (kc2 + (ci0 - 8) * 8);
  int scol1 = (ci1 < 8) ? (kc1 + ci1 * 8) : (kc2 + (ci1 - 8) * 8);

  s16x8 q1f[2], q2f[2];
  {
    size_t ro = (size_t)(b * N_ + qt * 128 + w * 16 + lr) * DQKV;
    q1f[0] = *(const s16x8*)(qkv + ro + qc1 + lk);
    q1f[1] = *(const s16x8*)(qkv + ro + qc1 + 32 + lk);
    q2f[0] = *(const s16x8*)(qkv + ro + qc2 + lk);
    q2f[1] = *(const s16x8*)(qkv + ro + qc2 + 32 + lk);
  }

#define STAGE_K(Lb, kt)                                                              \
  do {                                                                               \
    gload_lds16(kvbase + (size_t)((kt) * 64 + w * 8 + srw) * DQKV + scol0,           \
                (Lb) + (w * 8) * 128);                                               \
    gload_lds16(kvbase + (size_t)((kt) * 64 + w * 8 + 4 + srw) * DQKV + scol1,       \
                (Lb) + (w * 8 + 4) * 128);                                           \
  } while (0)

#define STAGE_K128(Lb, kt)                                                           \
  do {                                                                               \
    gload_lds16(kvbase + (size_t)((kt) * 128 + w * 16 + srw) * DQKV + scol0,         \
                (Lb) + (w * 16) * 128);                                              \
    gload_lds16(kvbase + (size_t)((kt) * 128 + w * 16 + 4 + srw) * DQKV + scol1,     \
                (Lb) + (w * 16 + 4) * 128);                                          \
    gload_lds16(kvbase + (size_t)((kt) * 128 + w * 16 + 8 + srw) * DQKV + scol0,     \
                (Lb) + (w * 16 + 8) * 128);                                          \
    gload_lds16(kvbase + (size_t)((kt) * 128 + w * 16 + 12 + srw) * DQKV + scol1,    \
                (Lb) + (w * 16 + 12) * 128);                                         \
  } while (0)

#define KREAD(Lb, row, colu) (*(const s16x8*)&(Lb)[(row) * 128 + ((colu) ^ (((row) & 7) * 8))])

  unsigned short* Kb0 = KP;
  unsigned short* Kb1 = KP + 8192;
  unsigned short* Pb  = KP + 16384;
  unsigned short* KA  = KP;          // pass-1 128-row buffers (overlay)
  unsigned short* KB  = KP + 16384;

  // ---------------- pass 1: l1,l2 (KVBLK=128, 8 iters) --------------------------
  float lp1[4] = {0.f, 0.f, 0.f, 0.f}, lp2[4] = {0.f, 0.f, 0.f, 0.f};
  {
    STAGE_K128(KA, 0);
    __syncthreads();
    for (int kt = 0; kt < 8; ++kt) {
      unsigned short* Lb = (kt & 1) ? KB : KA;
      STAGE_K128((kt & 1) ? KA : KB, (kt + 1) & 7);  // wraps: re-warms KA w/ tile 0
      f32x4 s1[8], s2[8];
      #pragma unroll
      for (int nf = 0; nf < 8; ++nf) {
        int row = nf * 16 + lr;
        s16x8 a0 = KREAD(Lb, row, lk);
        s16x8 a1 = KREAD(Lb, row, 32 + lk);
        s16x8 b0 = KREAD(Lb, row, 64 + lk);
        s16x8 b1 = KREAD(Lb, row, 96 + lk);
        f32x4 t1 = __builtin_amdgcn_mfma_f32_16x16x32_bf16(q1f[0], a0, zero, 0, 0, 0);
        s1[nf]   = __builtin_amdgcn_mfma_f32_16x16x32_bf16(q1f[1], a1, t1, 0, 0, 0);
        f32x4 t2 = __builtin_amdgcn_mfma_f32_16x16x32_bf16(q2f[0], b0, zero, 0, 0, 0);
        s2[nf]   = __builtin_amdgcn_mfma_f32_16x16x32_bf16(q2f[1], b1, t2, 0, 0, 0);
      }
      #pragma unroll
      for (int nf = 0; nf < 8; ++nf)
        #pragma unroll
        for (int r = 0; r < 4; ++r) {
          lp1[r] += __expf(s1[nf][r] * scale);
          lp2[r] += __expf(s2[nf][r] * scale);
        }
      __syncthreads();                 // stage drained; all K reads done
    }
    #pragma unroll
    for (int r = 0; r < 4; ++r)
      #pragma unroll
      for (int d = 1; d < 16; d <<= 1) {
        lp1[r] += __shfl_xor(lp1[r], d, 64);
        lp2[r] += __shfl_xor(lp2[r], d, 64);
      }
  }
  float lam = *lamp;
  float r1v[4], r2v[4];
  #pragma unroll
  for (int r = 0; r < 4; ++r) { r1v[r] = 1.f / lp1[r]; r2v[r] = lam / lp2[r]; }

  // ---------------- pass 2: overlapped pipeline (Kb0/Kb1 resident from wrap) ----
  f32x4 O[8][4];
  #pragma unroll
  for (int mf = 0; mf < 8; ++mf)
    #pragma unroll
    for (int nf = 0; nf < 4; ++nf) O[mf][nf] = zero;

  auto qk_to_p = [&](const unsigned short* Lb, unsigned short* Pt) {
    f32x4 s1[4], s2[4];
    #pragma unroll
    for (int nf = 0; nf < 4; ++nf) {
      int row = nf * 16 + lr;
      s16x8 a0 = KREAD(Lb, row, lk);
      s16x8 a1 = KREAD(Lb, row, 32 + lk);
      s16x8 b0 = KREAD(Lb, row, 64 + lk);
      s16x8 b1 = KREAD(Lb, row, 96 + lk);
      f32x4 t1 = __builtin_amdgcn_mfma_f32_16x16x32_bf16(q1f[0], a0, zero, 0, 0, 0);
      s1[nf]   = __builtin_amdgcn_mfma_f32_16x16x32_bf16(q1f[1], a1, t1, 0, 0, 0);
      f32x4 t2 = __builtin_amdgcn_mfma_f32_16x16x32_bf16(q2f[0], b0, zero, 0, 0, 0);
      s2[nf]   = __builtin_amdgcn_mfma_f32_16x16x32_bf16(q2f[1], b1, t2, 0, 0, 0);
    }
    #pragma unroll
    for (int nf = 0; nf < 4; ++nf)
      #pragma unroll
      for (int r = 0; r < 4; ++r) {
        float p = __expf(s1[nf][r] * scale) * r1v[r]
                - __expf(s2[nf][r] * scale) * r2v[r];
        Pt[(w * 16 + lg * 4 + r) * 68 + nf * 16 + lr] = f2bf(p);
      }
  };

  // pre-iter: QK(0) -> P[0] (Kb0 = first half of KA = kv 0..63); stage K(1)
  qk_to_p(Kb0, Pb);
  STAGE_K(Kb1, 1);
  WAITV(0);
  WAITL0();
  __builtin_amdgcn_s_barrier();

  for (int kt = 0; kt < 16; ++kt) {
    unsigned short* Pcur = Pb + (kt & 1) * 8704;
    unsigned short* Pnxt = Pb + ((kt + 1) & 1) * 8704;
    unsigned short* Knxt = ((kt + 1) & 1) ? Kb1 : Kb0;
    unsigned short* Kstg = (kt & 1) ? Kb1 : Kb0;
    int staged = 0;
    if (kt + 2 < 16) { STAGE_K(Kstg, kt + 2); staged = 1; }
    s16x8 vf[4][2];
    #pragma unroll
    for (int nf = 0; nf < 4; ++nf)
      #pragma unroll
      for (int kq = 0; kq < 2; ++kq)
        vf[nf][kq] = *(const s16x8*)(vt + (size_t)(bh * 512 + w * 64 + nf * 16 + lr) * N_
                                     + kt * 64 + kq * 32 + lk);
    if (kt + 1 < 16) qk_to_p(Knxt, Pnxt);
    __builtin_amdgcn_s_setprio(1);
    #pragma unroll
    for (int mf = 0; mf < 8; ++mf) {
      s16x8 pf0 = *(const s16x8*)&Pcur[(mf * 16 + lr) * 68 + lk];
      s16x8 pf1 = *(const s16x8*)&Pcur[(mf * 16 + lr) * 68 + 32 + lk];
      #pragma unroll
      for (int nf = 0; nf < 4; ++nf) {
        O[mf][nf] = __builtin_amdgcn_mfma_f32_16x16x32_bf16(pf0, vf[nf][0], O[mf][nf], 0, 0, 0);
        O[mf][nf] = __builtin_amdgcn_mfma_f32_16x16x32_bf16(pf1, vf[nf][1], O[mf][nf], 0, 0, 0);
      }
    }
    __builtin_amdgcn_s_setprio(0);
    if (kt < 15) {
      if (staged) { WAITV(8); }
      else        { WAITV(0); }
      WAITL0();
      __builtin_amdgcn_s_barrier();
    }
  }
#undef STAGE_K
#undef STAGE_K128
#undef KREAD
  // epilogue
  #pragma unroll
  for (int mf = 0; mf < 8; ++mf)
    #pragma unroll
    for (int nf = 0; nf < 4; ++nf) {
      int col = h * 512 + w * 64 + nf * 16 + lr;
      #pragma unroll
      for (int r = 0; r < 4; ++r) {
        int row = b * N_ + qt * 128 + mf * 16 + lg * 4 + r;
        aout[(size_t)row * DQKV + col] = f2bf(O[mf][nf][r]);
      }
    }
}

// ---------------------------------- launcher ------------------------------------
extern "C" void kernel_launch(void* const* d_in, const int* in_sizes, int n_in,
                              void* d_out, int out_size, void* d_ws, size_t ws_size,
                              hipStream_t stream) {
  const float* x    = (const float*)d_in[0];
  const float* t    = (const float*)d_in[1];
  const float* ln1g = (const float*)d_in[2];
  const float* ln1b = (const float*)d_in[3];
  const float* Wqkv = (const float*)d_in[4];
  const float* bqkv = (const float*)d_in[5];
  const float* lam  = (const float*)d_in[6];
  const float* Wm   = (const float*)d_in[7];
  const float* bm   = (const float*)d_in[8];
  const float* Wt1  = (const float*)d_in[9];
  const float* bt1  = (const float*)d_in[10];
  const float* Wt2  = (const float*)d_in[11];
  const float* bt2  = (const float*)d_in[12];
  const float* lnfg = (const float*)d_in[13];
  const float* lnfb = (const float*)d_in[14];
  const float* Wf1  = (const float*)d_in[15];
  const float* bf1  = (const float*)d_in[16];
  const float* Wf2  = (const float*)d_in[17];
  const float* bf2  = (const float*)d_in[18];
  float* out = (float*)d_out;
  char* ws = (char*)d_ws;

  // workspace layout (bytes), ~209 MB total
  unsigned short* qkv   = (unsigned short*)(ws);                  // [8192][6144] bf16 (100.7MB)
  unsigned short* vt    = (unsigned short*)(ws + 100663296ull);   // [64][512][1024] bf16 (67MB)
  float*          x2    = (float*)(ws + 167772160ull);            // [8192][512] f32 (16.8MB)
  unsigned short* xn    = (unsigned short*)(ws + 184549376ull);   // [8192][512] bf16 (xn, then h)
  unsigned short* WqkvT = (unsigned short*)(ws + 193986560ull);   // [6144][512]
  unsigned short* WmT   = (unsigned short*)(ws + 200278016ull);   // [512][4096]
  unsigned short* Wf1T  = (unsigned short*)(ws + 204472320ull);   // [2048][512]
  unsigned short* Wf2T  = (unsigned short*)(ws + 206569472ull);   // [512][2048]
  float*          tp    = (float*)(ws + 208666624ull);            // [8][512]
  unsigned short* ff1s  = qkv;          // alias: qkv dead after attention
  unsigned short* aout  = qkv + 2048;   // alias: attention out over dead V region

  // prep: 4x weight transpose + time MLP + LN1, one dispatch
  prep_k<<<15368, 256, 0, stream>>>(
      Wqkv, WqkvT, Wm, WmT, Wf1, Wf1T, Wf2, Wf2T,
      t, Wt1, bt1, Wt2, bt2, tp, x, ln1g, ln1b, xn);
  // qkv GEMM (V columns written directly transposed into vt)
  gemm_bt<3><<<dim3(DQKV / 128, 8192 / 128), 256, 0, stream>>>(
      xn, DIN, WqkvT, bqkv, nullptr, qkv, DQKV, DQKV, DIN, vt);
  // fused two-pass differential attention (QBLK=128, KVBLK=128 pass 1)
  attn_k<<<512, 512, 0, stream>>>(qkv, vt, lam, aout);
  // x2 = x + attn_out @ Wm + bm  (64x128 tile, 3-stage pipeline)
  gemm_bt64<<<dim3(DIN / 128, 8192 / 64), 256, 0, stream>>>(
      aout, DQKV, WmT, bm, x, x2, DIN, DIN, 4096);
  // h = LN(x2 + tp)
  ln_k<<<8192, 256, 0, stream>>>(x2, tp, lnfg, lnfb, xn);
  // ff1 = swish(h @ Wf1 + bf1)
  gemm_bt<1><<<dim3(DEXP / 128, 8192 / 128), 256, 0, stream>>>(
      xn, DIN, Wf1T, bf1, nullptr, ff1s, DEXP, DEXP, DIN, nullptr);
  // out = x2 + ff1 @ Wf2 + bf2  (64x128 tile, 3-stage pipeline)
  gemm_bt64<<<dim3(DIN / 128, 8192 / 64), 256, 0, stream>>>(
      ff1s, DEXP, Wf2T, bf2, x2, out, DIN, DIN, DEXP);
}

// Round 24
// 448.989 us; speedup vs baseline: 1.0092x; 1.0092x over previous
//
#include <hip/hip_runtime.h>

// Problem dims
#define B_    8
#define N_    1024
#define DIN   512
#define H_    8
#define DH    64
#define DQKV  6144   // 2*DQ + 2*DQ + DV = 512+512+512+512+4096
#define DEXP  2048
#define DTIME 256

typedef __attribute__((ext_vector_type(8))) short s16x8;   // 8 bf16 (MFMA A/B frag)
typedef __attribute__((ext_vector_type(4))) short s16x4;
typedef __attribute__((ext_vector_type(4))) float f32x4;   // MFMA C/D frag

__device__ __forceinline__ unsigned short f2bf(float f) {
  unsigned int u = __float_as_uint(f);
  u = (u + 0x7fffu + ((u >> 16) & 1u)) >> 16;   // RNE
  return (unsigned short)u;
}

__device__ __forceinline__ void gload_lds16(const unsigned short* g, unsigned short* l) {
  __builtin_amdgcn_global_load_lds(
      (const __attribute__((address_space(1))) unsigned int*)(g),
      (__attribute__((address_space(3))) unsigned int*)(l), 16, 0, 0);
}

#define WAITV(n) do { asm volatile("s_waitcnt vmcnt(" #n ")" ::: "memory"); \
                      __builtin_amdgcn_sched_barrier(0); } while (0)
#define WAITL0() do { asm volatile("s_waitcnt lgkmcnt(0)" ::: "memory"); \
                      __builtin_amdgcn_sched_barrier(0); } while (0)

// ---------------- prep mega-kernel: 4x weight-transpose + time MLP + LN1 --------
// blocks [0,7168): 32x32 f32->bf16T tiles; [7168,7176): time MLP; rest: LN rows.
__global__ __launch_bounds__(256) void prep_k(
    const float* __restrict__ Wqkv, unsigned short* __restrict__ WqkvT,
    const float* __restrict__ Wm,   unsigned short* __restrict__ WmT,
    const float* __restrict__ Wf1,  unsigned short* __restrict__ Wf1T,
    const float* __restrict__ Wf2,  unsigned short* __restrict__ Wf2T,
    const float* __restrict__ t,    const float* __restrict__ Wt1,
    const float* __restrict__ bt1,  const float* __restrict__ Wt2,
    const float* __restrict__ bt2,  float* __restrict__ tp,
    const float* __restrict__ x,    const float* __restrict__ ln1g,
    const float* __restrict__ ln1b, unsigned short* __restrict__ xn)
{
  __shared__ float tile[32][33];
  __shared__ float tl[256], hl[256];
  __shared__ float red[8];
  int bid = blockIdx.x;
  int tid = threadIdx.x;
  if (bid < 7168) {
    const float* in; unsigned short* out; int R, C, gx, gy;
    if (bid < 3072)      { in = Wqkv; out = WqkvT; R = 512;  C = 6144; gx = bid % 192;          gy = bid / 192; }
    else if (bid < 5120) { int b2 = bid - 3072; in = Wm;  out = WmT;  R = 4096; C = 512;  gx = b2 % 16; gy = b2 / 16; }
    else if (bid < 6144) { int b3 = bid - 5120; in = Wf1; out = Wf1T; R = 512;  C = 2048; gx = b3 % 64; gy = b3 / 64; }
    else                 { int b4 = bid - 6144; in = Wf2; out = Wf2T; R = 2048; C = 512;  gx = b4 % 16; gy = b4 / 16; }
    int tx = tid & 31, ty = tid >> 5;
    int c0 = gx * 32, r0 = gy * 32;
    #pragma unroll
    for (int k = 0; k < 4; ++k)
      tile[ty + k * 8][tx] = in[(size_t)(r0 + ty + k * 8) * C + c0 + tx];
    __syncthreads();
    #pragma unroll
    for (int k = 0; k < 4; ++k)
      out[(size_t)(c0 + ty + k * 8) * R + r0 + tx] = f2bf(tile[tx][ty + k * 8]);
    return;
  }
  if (bid < 7176) {
    int b = bid - 7168;
    tl[tid] = t[(size_t)b * 256 + tid];
    __syncthreads();
    float a = bt1[tid];
    for (int k = 0; k < 256; ++k) a += tl[k] * Wt1[(size_t)k * 256 + tid];
    hl[tid] = a / (1.0f + __expf(-a));
    __syncthreads();
    for (int j = tid; j < 512; j += 256) {
      float a2 = bt2[j];
      for (int k = 0; k < 256; ++k) a2 += hl[k] * Wt2[(size_t)k * 512 + j];
      tp[(size_t)b * 512 + j] = a2;
    }
    return;
  }
  int row = bid - 7176;
  const float* xr = x + (size_t)row * DIN;
  float v0 = xr[tid], v1 = xr[tid + 256];
  float s = v0 + v1, sq = v0 * v0 + v1 * v1;
  #pragma unroll
  for (int m = 1; m < 64; m <<= 1) { s += __shfl_xor(s, m, 64); sq += __shfl_xor(sq, m, 64); }
  int w = tid >> 6;
  if ((tid & 63) == 0) { red[w] = s; red[4 + w] = sq; }
  __syncthreads();
  s  = red[0] + red[1] + red[2] + red[3];
  sq = red[4] + red[5] + red[6] + red[7];
  float mean = s * (1.0f / DIN);
  float var  = sq * (1.0f / DIN) - mean * mean;
  float rs = rsqrtf(var + 1e-5f);
  unsigned short* orow = xn + (size_t)row * DIN;
  orow[tid]       = f2bf((v0 - mean) * rs * ln1g[tid]       + ln1b[tid]);
  orow[tid + 256] = f2bf((v1 - mean) * rs * ln1g[tid + 256] + ln1b[tid + 256]);
}

// ---------------- LayerNorm (D=512), additive per-batch row, bf16 out -----------
__global__ __launch_bounds__(256) void ln_k(
    const float* __restrict__ x, const float* __restrict__ add,
    const float* __restrict__ g, const float* __restrict__ bb,
    unsigned short* __restrict__ out)
{
  int row = blockIdx.x;
  int tid = threadIdx.x;
  const float* xr = x + (size_t)row * DIN;
  float v0 = xr[tid], v1 = xr[tid + 256];
  if (add) {
    const float* ar = add + (size_t)(row >> 10) * DIN;   // row/1024 = batch idx
    v0 += ar[tid]; v1 += ar[tid + 256];
  }
  float s = v0 + v1, sq = v0 * v0 + v1 * v1;
  #pragma unroll
  for (int m = 1; m < 64; m <<= 1) { s += __shfl_xor(s, m, 64); sq += __shfl_xor(sq, m, 64); }
  __shared__ float red[8];
  int w = tid >> 6;
  if ((tid & 63) == 0) { red[w] = s; red[4 + w] = sq; }
  __syncthreads();
  s  = red[0] + red[1] + red[2] + red[3];
  sq = red[4] + red[5] + red[6] + red[7];
  float mean = s * (1.0f / DIN);
  float var  = sq * (1.0f / DIN) - mean * mean;
  float rs = rsqrtf(var + 1e-5f);
  unsigned short* orow = out + (size_t)row * DIN;
  orow[tid]       = f2bf((v0 - mean) * rs * g[tid]       + bb[tid]);
  orow[tid + 256] = f2bf((v1 - mean) * rs * g[tid + 256] + bb[tid + 256]);
}

#define GSWZ(Lb, base, row, colu) \
  (*(const s16x8*)&(Lb)[(base) + (row) * 64 + (((colu) ^ (((row) & 7) * 8)))])

// ---------------- bf16 MFMA GEMM: C = epi(A @ Bt^T + bias [+res]) ---------------
// 128x128 tile, BK=64, 4 waves; double-buffered LDS, 1 barrier/k-step.
template<int EPI>
__global__ __launch_bounds__(256) void gemm_bt(
    const unsigned short* __restrict__ A, int lda,
    const unsigned short* __restrict__ Bt,
    const float* __restrict__ bias, const float* __restrict__ res,
    void* __restrict__ C, int ldc, int N, int K,
    unsigned short* __restrict__ vtout)
{
  __shared__ __attribute__((aligned(16))) unsigned short As[2 * 8192]; // 128x64 x2
  __shared__ __attribute__((aligned(16))) unsigned short Bs[2 * 8192];
  int tid = threadIdx.x;
  int m0 = blockIdx.y * 128, n0 = blockIdx.x * 128;
  int lane = tid & 63, wid = tid >> 6;
  int wr = wid >> 1, wc = wid & 1;
  int lr = lane & 15, lg = lane >> 4, lk = lg * 8;
  f32x4 zero = {0.f, 0.f, 0.f, 0.f};
  f32x4 acc[4][4];
  #pragma unroll
  for (int i = 0; i < 4; ++i)
    #pragma unroll
    for (int j = 0; j < 4; ++j) acc[i][j] = zero;
  int srow = wid * 8 + (lane >> 3);
  int scol = ((lane & 7) ^ (lane >> 3)) * 8;
  const unsigned short* gA = A  + (size_t)(m0 + srow) * lda + scol;
  const unsigned short* gB = Bt + (size_t)(n0 + srow) * K + scol;
  int nk = K >> 6;
  #pragma unroll
  for (int i = 0; i < 4; ++i) {
    gload_lds16(gA + (size_t)(i * 32) * lda, As + (i * 32 + wid * 8) * 64);
    gload_lds16(gB + (size_t)(i * 32) * K,   Bs + (i * 32 + wid * 8) * 64);
  }
  __syncthreads();
  for (int kq = 0; kq < nk; ++kq) {
    int cur = (kq & 1) * 8192;
    if (kq + 1 < nk) {
      int nxt = ((kq + 1) & 1) * 8192;
      int kt = (kq + 1) * 64;
      #pragma unroll
      for (int i = 0; i < 4; ++i) {
        gload_lds16(gA + (size_t)(i * 32) * lda + kt, As + nxt + (i * 32 + wid * 8) * 64);
        gload_lds16(gB + (size_t)(i * 32) * K   + kt, Bs + nxt + (i * 32 + wid * 8) * 64);
      }
    }
    s16x8 af[4][2], bf[4][2];
    #pragma unroll
    for (int mf = 0; mf < 4; ++mf) {
      int row = wr * 64 + mf * 16 + lr;
      af[mf][0] = GSWZ(As, cur, row, lk);
      af[mf][1] = GSWZ(As, cur, row, 32 + lk);
    }
    #pragma unroll
    for (int nf = 0; nf < 4; ++nf) {
      int row = wc * 64 + nf * 16 + lr;
      bf[nf][0] = GSWZ(Bs, cur, row, lk);
      bf[nf][1] = GSWZ(Bs, cur, row, 32 + lk);
    }
    #pragma unroll
    for (int mf = 0; mf < 4; ++mf)
      #pragma unroll
      for (int nf = 0; nf < 4; ++nf) {
        acc[mf][nf] = __builtin_amdgcn_mfma_f32_16x16x32_bf16(af[mf][0], bf[nf][0], acc[mf][nf], 0, 0, 0);
        acc[mf][nf] = __builtin_amdgcn_mfma_f32_16x16x32_bf16(af[mf][1], bf[nf][1], acc[mf][nf], 0, 0, 0);
      }
    __syncthreads();
  }
  if (EPI == 3 && n0 >= 2048) {
    #pragma unroll
    for (int mf = 0; mf < 4; ++mf) {
      int row = m0 + wr * 64 + mf * 16 + lg * 4;
      int bb = row >> 10, nn = row & 1023;
      #pragma unroll
      for (int nf = 0; nf < 4; ++nf) {
        int col = n0 + wc * 64 + nf * 16 + lr;
        float bcol = bias[col];
        int hc = col - 2048;
        int hh = hc >> 9, cc = hc & 511;
        unsigned short pk[4];
        #pragma unroll
        for (int r = 0; r < 4; ++r) pk[r] = f2bf(acc[mf][nf][r] + bcol);
        *(s16x4*)(vtout + ((size_t)((bb * 8 + hh) * 512 + cc)) * 1024 + nn) = *(const s16x4*)pk;
      }
    }
    return;
  }
  #pragma unroll
  for (int mf = 0; mf < 4; ++mf)
    #pragma unroll
    for (int nf = 0; nf < 4; ++nf) {
      int col = n0 + wc * 64 + nf * 16 + lr;
      float bcol = bias[col];
      #pragma unroll
      for (int r = 0; r < 4; ++r) {
        int row = m0 + wr * 64 + mf * 16 + lg * 4 + r;
        float v = acc[mf][nf][r] + bcol;
        if (EPI == 1) v = v / (1.0f + __expf(-v));            // swish
        if (EPI == 2) {
          v += res[(size_t)row * N + col];
          ((float*)C)[(size_t)row * ldc + col] = v;
        } else {
          ((unsigned short*)C)[(size_t)row * ldc + col] = f2bf(v);
        }
      }
    }
}

// ---------------- 64x128 GEMM (bias + f32 residual) for N=512 K-heavy shapes ----
__global__ __launch_bounds__(256) void gemm_bt64(
    const unsigned short* __restrict__ A, int lda,
    const unsigned short* __restrict__ Bt,
    const float* __restrict__ bias, const float* __restrict__ res,
    float* __restrict__ C, int ldc, int N, int K)
{
  __shared__ __attribute__((aligned(16))) unsigned short As[2 * 4096]; // 64x64 x2
  __shared__ __attribute__((aligned(16))) unsigned short Bs[2 * 8192]; // 128x64 x2
  int tid = threadIdx.x;
  int m0 = blockIdx.y * 64, n0 = blockIdx.x * 128;
  int lane = tid & 63, wid = tid >> 6;
  int lr = lane & 15, lg = lane >> 4, lk = lg * 8;
  f32x4 zero = {0.f, 0.f, 0.f, 0.f};
  f32x4 acc[4][2];
  #pragma unroll
  for (int i = 0; i < 4; ++i) { acc[i][0] = zero; acc[i][1] = zero; }
  int srow = wid * 8 + (lane >> 3);          // 0..31
  int scol = ((lane & 7) ^ (lane >> 3)) * 8;
  const unsigned short* gA = A  + (size_t)(m0 + srow) * lda + scol;
  const unsigned short* gB = Bt + (size_t)(n0 + srow) * K + scol;
  int nk = K >> 6;
  #pragma unroll
  for (int i = 0; i < 2; ++i)
    gload_lds16(gA + (size_t)(i * 32) * lda, As + (i * 32 + wid * 8) * 64);
  #pragma unroll
  for (int i = 0; i < 4; ++i)
    gload_lds16(gB + (size_t)(i * 32) * K, Bs + (i * 32 + wid * 8) * 64);
  __syncthreads();
  for (int kq = 0; kq < nk; ++kq) {
    int curA = (kq & 1) * 4096;
    int curB = (kq & 1) * 8192;
    if (kq + 1 < nk) {
      int nxtA = ((kq + 1) & 1) * 4096;
      int nxtB = ((kq + 1) & 1) * 8192;
      int kt = (kq + 1) * 64;
      #pragma unroll
      for (int i = 0; i < 2; ++i)
        gload_lds16(gA + (size_t)(i * 32) * lda + kt, As + nxtA + (i * 32 + wid * 8) * 64);
      #pragma unroll
      for (int i = 0; i < 4; ++i)
        gload_lds16(gB + (size_t)(i * 32) * K + kt, Bs + nxtB + (i * 32 + wid * 8) * 64);
    }
    s16x8 af[4][2], bf[2][2];
    #pragma unroll
    for (int mf = 0; mf < 4; ++mf) {
      int row = mf * 16 + lr;
      af[mf][0] = GSWZ(As, curA, row, lk);
      af[mf][1] = GSWZ(As, curA, row, 32 + lk);
    }
    #pragma unroll
    for (int nf = 0; nf < 2; ++nf) {
      int row = wid * 32 + nf * 16 + lr;
      bf[nf][0] = GSWZ(Bs, curB, row, lk);
      bf[nf][1] = GSWZ(Bs, curB, row, 32 + lk);
    }
    #pragma unroll
    for (int mf = 0; mf < 4; ++mf)
      #pragma unroll
      for (int nf = 0; nf < 2; ++nf) {
        acc[mf][nf] = __builtin_amdgcn_mfma_f32_16x16x32_bf16(af[mf][0], bf[nf][0], acc[mf][nf], 0, 0, 0);
        acc[mf][nf] = __builtin_amdgcn_mfma_f32_16x16x32_bf16(af[mf][1], bf[nf][1], acc[mf][nf], 0, 0, 0);
      }
    __syncthreads();
  }
  #pragma unroll
  for (int mf = 0; mf < 4; ++mf)
    #pragma unroll
    for (int nf = 0; nf < 2; ++nf) {
      int col = n0 + wid * 32 + nf * 16 + lr;
      float bcol = bias[col];
      #pragma unroll
      for (int r = 0; r < 4; ++r) {
        int row = m0 + mf * 16 + lg * 4 + r;
        C[(size_t)row * ldc + col] = acc[mf][nf][r] + bcol + res[(size_t)row * N + col];
      }
    }
}

// ---------------- fused differential attention, QBLK=128 (r20-exact) ------------
__global__ __launch_bounds__(512) void attn_k(
    const unsigned short* __restrict__ qkv, const unsigned short* __restrict__ vt,
    const float* __restrict__ lamp, unsigned short* __restrict__ aout /* = qkv+2048 */)
{
  const float scale = 0.125f;
  __shared__ __attribute__((aligned(16))) unsigned short KP[33792];
  int w0 = blockIdx.x;
  int bx = (w0 & 7) * 64 + (w0 >> 3);         // 512 blocks, bijective XCD swizzle
  int bh = bx >> 3, qt = bx & 7;
  int b = bh >> 3, h = bh & 7;
  int tid = threadIdx.x;
  int lane = tid & 63, w = tid >> 6;
  int lr = lane & 15, lg = lane >> 4, lk = lg * 8;
  int qc1 = h * 64, qc2 = 512 + h * 64, kc1 = 1024 + h * 64, kc2 = 1536 + h * 64;
  f32x4 zero = {0.f, 0.f, 0.f, 0.f};
  const unsigned short* kvbase = qkv + (size_t)(b * N_) * DQKV;

  int srw = lane >> 4;                        // 0..3
  int ci0 = (lane & 15) ^ srw;
  int ci1 = (lane & 15) ^ (4 + srw);
  int scol0 = (ci0 < 8) ? (kc1 + ci0 * 8) : (kc2 + (ci0 - 8) * 8);
  int scol1 = (ci1 < 8) ? (kc1 + ci1 * 8) : (kc2 + (ci1 - 8) * 8);

  s16x8 q1f[2], q2f[2];
  {
    size_t ro = (size_t)(b * N_ + qt * 128 + w * 16 + lr) * DQKV;
    q1f[0] = *(const s16x8*)(qkv + ro + qc1 + lk);
    q1f[1] = *(const s16x8*)(qkv + ro + qc1 + 32 + lk);
    q2f[0] = *(const s16x8*)(qkv + ro + qc2 + lk);
    q2f[1] = *(const s16x8*)(qkv + ro + qc2 + 32 + lk);
  }

#define STAGE_K(Lb, kt)                                                              \
  do {                                                                               \
    gload_lds16(kvbase + (size_t)((kt) * 64 + w * 8 + srw) * DQKV + scol0,           \
                (Lb) + (w * 8) * 128);                                               \
    gload_lds16(kvbase + (size_t)((kt) * 64 + w * 8 + 4 + srw) * DQKV + scol1,       \
                (Lb) + (w * 8 + 4) * 128);                                           \
  } while (0)

#define STAGE_K128(Lb, kt)                                                           \
  do {                                                                               \
    gload_lds16(kvbase + (size_t)((kt) * 128 + w * 16 + srw) * DQKV + scol0,         \
                (Lb) + (w * 16) * 128);                                              \
    gload_lds16(kvbase + (size_t)((kt) * 128 + w * 16 + 4 + srw) * DQKV + scol1,     \
                (Lb) + (w * 16 + 4) * 128);                                          \
    gload_lds16(kvbase + (size_t)((kt) * 128 + w * 16 + 8 + srw) * DQKV + scol0,     \
                (Lb) + (w * 16 + 8) * 128);                                          \
    gload_lds16(kvbase + (size_t)((kt) * 128 + w * 16 + 12 + srw) * DQKV + scol1,    \
                (Lb) + (w * 16 + 12) * 128);                                         \
  } while (0)

#define KREAD(Lb, row, colu) (*(const s16x8*)&(Lb)[(row) * 128 + ((colu) ^ (((row) & 7) * 8))])

  unsigned short* Kb0 = KP;
  unsigned short* Kb1 = KP + 8192;
  unsigned short* Pb  = KP + 16384;
  unsigned short* KA  = KP;          // pass-1 128-row buffers (overlay)
  unsigned short* KB  = KP + 16384;

  // ---------------- pass 1: l1,l2 (KVBLK=128, 8 iters) --------------------------
  float lp1[4] = {0.f, 0.f, 0.f, 0.f}, lp2[4] = {0.f, 0.f, 0.f, 0.f};
  {
    STAGE_K128(KA, 0);
    __syncthreads();
    for (int kt = 0; kt < 8; ++kt) {
      unsigned short* Lb = (kt & 1) ? KB : KA;
      STAGE_K128((kt & 1) ? KA : KB, (kt + 1) & 7);  // wraps: re-warms KA w/ tile 0
      f32x4 s1[8], s2[8];
      #pragma unroll
      for (int nf = 0; nf < 8; ++nf) {
        int row = nf * 16 + lr;
        s16x8 a0 = KREAD(Lb, row, lk);
        s16x8 a1 = KREAD(Lb, row, 32 + lk);
        s16x8 b0 = KREAD(Lb, row, 64 + lk);
        s16x8 b1 = KREAD(Lb, row, 96 + lk);
        f32x4 t1 = __builtin_amdgcn_mfma_f32_16x16x32_bf16(q1f[0], a0, zero, 0, 0, 0);
        s1[nf]   = __builtin_amdgcn_mfma_f32_16x16x32_bf16(q1f[1], a1, t1, 0, 0, 0);
        f32x4 t2 = __builtin_amdgcn_mfma_f32_16x16x32_bf16(q2f[0], b0, zero, 0, 0, 0);
        s2[nf]   = __builtin_amdgcn_mfma_f32_16x16x32_bf16(q2f[1], b1, t2, 0, 0, 0);
      }
      #pragma unroll
      for (int nf = 0; nf < 8; ++nf)
        #pragma unroll
        for (int r = 0; r < 4; ++r) {
          lp1[r] += __expf(s1[nf][r] * scale);
          lp2[r] += __expf(s2[nf][r] * scale);
        }
      __syncthreads();                 // stage drained; all K reads done
    }
    #pragma unroll
    for (int r = 0; r < 4; ++r)
      #pragma unroll
      for (int d = 1; d < 16; d <<= 1) {
        lp1[r] += __shfl_xor(lp1[r], d, 64);
        lp2[r] += __shfl_xor(lp2[r], d, 64);
      }
  }
  float lam = *lamp;
  float r1v[4], r2v[4];
  #pragma unroll
  for (int r = 0; r < 4; ++r) { r1v[r] = 1.f / lp1[r]; r2v[r] = lam / lp2[r]; }

  // ---------------- pass 2: overlapped pipeline (Kb0/Kb1 resident from wrap) ----
  f32x4 O[8][4];
  #pragma unroll
  for (int mf = 0; mf < 8; ++mf)
    #pragma unroll
    for (int nf = 0; nf < 4; ++nf) O[mf][nf] = zero;

  auto qk_to_p = [&](const unsigned short* Lb, unsigned short* Pt) {
    f32x4 s1[4], s2[4];
    #pragma unroll
    for (int nf = 0; nf < 4; ++nf) {
      int row = nf * 16 + lr;
      s16x8 a0 = KREAD(Lb, row, lk);
      s16x8 a1 = KREAD(Lb, row, 32 + lk);
      s16x8 b0 = KREAD(Lb, row, 64 + lk);
      s16x8 b1 = KREAD(Lb, row, 96 + lk);
      f32x4 t1 = __builtin_amdgcn_mfma_f32_16x16x32_bf16(q1f[0], a0, zero, 0, 0, 0);
      s1[nf]   = __builtin_amdgcn_mfma_f32_16x16x32_bf16(q1f[1], a1, t1, 0, 0, 0);
      f32x4 t2 = __builtin_amdgcn_mfma_f32_16x16x32_bf16(q2f[0], b0, zero, 0, 0, 0);
      s2[nf]   = __builtin_amdgcn_mfma_f32_16x16x32_bf16(q2f[1], b1, t2, 0, 0, 0);
    }
    #pragma unroll
    for (int nf = 0; nf < 4; ++nf)
      #pragma unroll
      for (int r = 0; r < 4; ++r) {
        float p = __expf(s1[nf][r] * scale) * r1v[r]
                - __expf(s2[nf][r] * scale) * r2v[r];
        Pt[(w * 16 + lg * 4 + r) * 68 + nf * 16 + lr] = f2bf(p);
      }
  };

  // pre-iter: QK(0) -> P[0] (Kb0 = first half of KA = kv 0..63); stage K(1)
  qk_to_p(Kb0, Pb);
  STAGE_K(Kb1, 1);
  WAITV(0);
  WAITL0();
  __builtin_amdgcn_s_barrier();

  for (int kt = 0; kt < 16; ++kt) {
    unsigned short* Pcur = Pb + (kt & 1) * 8704;
    unsigned short* Pnxt = Pb + ((kt + 1) & 1) * 8704;
    unsigned short* Knxt = ((kt + 1) & 1) ? Kb1 : Kb0;
    unsigned short* Kstg = (kt & 1) ? Kb1 : Kb0;
    int staged = 0;
    if (kt + 2 < 16) { STAGE_K(Kstg, kt + 2); staged = 1; }
    s16x8 vf[4][2];
    #pragma unroll
    for (int nf = 0; nf < 4; ++nf)
      #pragma unroll
      for (int kq = 0; kq < 2; ++kq)
        vf[nf][kq] = *(const s16x8*)(vt + (size_t)(bh * 512 + w * 64 + nf * 16 + lr) * N_
                                     + kt * 64 + kq * 32 + lk);
    if (kt + 1 < 16) qk_to_p(Knxt, Pnxt);
    __builtin_amdgcn_s_setprio(1);
    #pragma unroll
    for (int mf = 0; mf < 8; ++mf) {
      s16x8 pf0 = *(const s16x8*)&Pcur[(mf * 16 + lr) * 68 + lk];
      s16x8 pf1 = *(const s16x8*)&Pcur[(mf * 16 + lr) * 68 + 32 + lk];
      #pragma unroll
      for (int nf = 0; nf < 4; ++nf) {
        O[mf][nf] = __builtin_amdgcn_mfma_f32_16x16x32_bf16(pf0, vf[nf][0], O[mf][nf], 0, 0, 0);
        O[mf][nf] = __builtin_amdgcn_mfma_f32_16x16x32_bf16(pf1, vf[nf][1], O[mf][nf], 0, 0, 0);
      }
    }
    __builtin_amdgcn_s_setprio(0);
    if (kt < 15) {
      if (staged) { WAITV(8); }
      else        { WAITV(0); }
      WAITL0();
      __builtin_amdgcn_s_barrier();
    }
  }
#undef STAGE_K
#undef STAGE_K128
#undef KREAD
  // epilogue
  #pragma unroll
  for (int mf = 0; mf < 8; ++mf)
    #pragma unroll
    for (int nf = 0; nf < 4; ++nf) {
      int col = h * 512 + w * 64 + nf * 16 + lr;
      #pragma unroll
      for (int r = 0; r < 4; ++r) {
        int row = b * N_ + qt * 128 + mf * 16 + lg * 4 + r;
        aout[(size_t)row * DQKV + col] = f2bf(O[mf][nf][r]);
      }
    }
}

// ---------------------------------- launcher ------------------------------------
extern "C" void kernel_launch(void* const* d_in, const int* in_sizes, int n_in,
                              void* d_out, int out_size, void* d_ws, size_t ws_size,
                              hipStream_t stream) {
  const float* x    = (const float*)d_in[0];
  const float* t    = (const float*)d_in[1];
  const float* ln1g = (const float*)d_in[2];
  const float* ln1b = (const float*)d_in[3];
  const float* Wqkv = (const float*)d_in[4];
  const float* bqkv = (const float*)d_in[5];
  const float* lam  = (const float*)d_in[6];
  const float* Wm   = (const float*)d_in[7];
  const float* bm   = (const float*)d_in[8];
  const float* Wt1  = (const float*)d_in[9];
  const float* bt1  = (const float*)d_in[10];
  const float* Wt2  = (const float*)d_in[11];
  const float* bt2  = (const float*)d_in[12];
  const float* lnfg = (const float*)d_in[13];
  const float* lnfb = (const float*)d_in[14];
  const float* Wf1  = (const float*)d_in[15];
  const float* bf1  = (const float*)d_in[16];
  const float* Wf2  = (const float*)d_in[17];
  const float* bf2  = (const float*)d_in[18];
  float* out = (float*)d_out;
  char* ws = (char*)d_ws;

  // workspace layout (bytes), ~209 MB total
  unsigned short* qkv   = (unsigned short*)(ws);                  // [8192][6144] bf16 (100.7MB)
  unsigned short* vt    = (unsigned short*)(ws + 100663296ull);   // [64][512][1024] bf16 (67MB)
  float*          x2    = (float*)(ws + 167772160ull);            // [8192][512] f32 (16.8MB)
  unsigned short* xn    = (unsigned short*)(ws + 184549376ull);   // [8192][512] bf16 (xn, then h)
  unsigned short* WqkvT = (unsigned short*)(ws + 193986560ull);   // [6144][512]
  unsigned short* WmT   = (unsigned short*)(ws + 200278016ull);   // [512][4096]
  unsigned short* Wf1T  = (unsigned short*)(ws + 204472320ull);   // [2048][512]
  unsigned short* Wf2T  = (unsigned short*)(ws + 206569472ull);   // [512][2048]
  float*          tp    = (float*)(ws + 208666624ull);            // [8][512]
  unsigned short* ff1s  = qkv;          // alias: qkv dead after attention
  unsigned short* aout  = qkv + 2048;   // alias: attention out over dead V region

  // prep: 4x weight transpose + time MLP + LN1, one dispatch
  prep_k<<<15368, 256, 0, stream>>>(
      Wqkv, WqkvT, Wm, WmT, Wf1, Wf1T, Wf2, Wf2T,
      t, Wt1, bt1, Wt2, bt2, tp, x, ln1g, ln1b, xn);
  // qkv GEMM (V columns written directly transposed into vt)
  gemm_bt<3><<<dim3(DQKV / 128, 8192 / 128), 256, 0, stream>>>(
      xn, DIN, WqkvT, bqkv, nullptr, qkv, DQKV, DQKV, DIN, vt);
  // fused two-pass differential attention (QBLK=128, KVBLK=128 pass 1)
  attn_k<<<512, 512, 0, stream>>>(qkv, vt, lam, aout);
  // x2 = x + attn_out @ Wm + bm  (64x128 tile: 512 blocks, 3 blocks/CU)
  gemm_bt64<<<dim3(DIN / 128, 8192 / 64), 256, 0, stream>>>(
      aout, DQKV, WmT, bm, x, x2, DIN, DIN, 4096);
  // h = LN(x2 + tp)
  ln_k<<<8192, 256, 0, stream>>>(x2, tp, lnfg, lnfb, xn);
  // ff1 = swish(h @ Wf1 + bf1)
  gemm_bt<1><<<dim3(DEXP / 128, 8192 / 128), 256, 0, stream>>>(
      xn, DIN, Wf1T, bf1, nullptr, ff1s, DEXP, DEXP, DIN, nullptr);
  // out = x2 + ff1 @ Wf2 + bf2  (64x128 tile)
  gemm_bt64<<<dim3(DIN / 128, 8192 / 64), 256, 0, stream>>>(
      ff1s, DEXP, Wf2T, bf2, x2, out, DIN, DIN, DEXP);
}

// Round 25
// 393.687 us; speedup vs baseline: 1.1509x; 1.1405x over previous
//
#include <hip/hip_runtime.h>

// Problem dims
#define B_    8
#define N_    1024
#define DIN   512
#define H_    8
#define DH    64
#define DQKV  6144   // 2*DQ + 2*DQ + DV = 512+512+512+512+4096
#define DEXP  2048
#define DTIME 256

typedef __attribute__((ext_vector_type(8))) short s16x8;   // 8 bf16 (MFMA A/B frag)
typedef __attribute__((ext_vector_type(4))) short s16x4;
typedef __attribute__((ext_vector_type(4))) float f32x4;   // MFMA C/D frag

__device__ __forceinline__ unsigned short f2bf(float f) {
  unsigned int u = __float_as_uint(f);
  u = (u + 0x7fffu + ((u >> 16) & 1u)) >> 16;   // RNE
  return (unsigned short)u;
}

__device__ __forceinline__ void gload_lds16(const unsigned short* g, unsigned short* l) {
  __builtin_amdgcn_global_load_lds(
      (const __attribute__((address_space(1))) unsigned int*)(g),
      (__attribute__((address_space(3))) unsigned int*)(l), 16, 0, 0);
}

#define WAITV(n) do { asm volatile("s_waitcnt vmcnt(" #n ")" ::: "memory"); \
                      __builtin_amdgcn_sched_barrier(0); } while (0)
#define WAITL0() do { asm volatile("s_waitcnt lgkmcnt(0)" ::: "memory"); \
                      __builtin_amdgcn_sched_barrier(0); } while (0)

// ---------------- prep mega-kernel: 4x weight-transpose + time MLP + LN1 --------
// blocks [0,7168): 32x32 f32->bf16T tiles; [7168,7176): time MLP; rest: LN rows.
__global__ __launch_bounds__(256) void prep_k(
    const float* __restrict__ Wqkv, unsigned short* __restrict__ WqkvT,
    const float* __restrict__ Wm,   unsigned short* __restrict__ WmT,
    const float* __restrict__ Wf1,  unsigned short* __restrict__ Wf1T,
    const float* __restrict__ Wf2,  unsigned short* __restrict__ Wf2T,
    const float* __restrict__ t,    const float* __restrict__ Wt1,
    const float* __restrict__ bt1,  const float* __restrict__ Wt2,
    const float* __restrict__ bt2,  float* __restrict__ tp,
    const float* __restrict__ x,    const float* __restrict__ ln1g,
    const float* __restrict__ ln1b, unsigned short* __restrict__ xn)
{
  __shared__ float tile[32][33];
  __shared__ float tl[256], hl[256];
  __shared__ float red[8];
  int bid = blockIdx.x;
  int tid = threadIdx.x;
  if (bid < 7168) {
    const float* in; unsigned short* out; int R, C, gx, gy;
    if (bid < 3072)      { in = Wqkv; out = WqkvT; R = 512;  C = 6144; gx = bid % 192;          gy = bid / 192; }
    else if (bid < 5120) { int b2 = bid - 3072; in = Wm;  out = WmT;  R = 4096; C = 512;  gx = b2 % 16; gy = b2 / 16; }
    else if (bid < 6144) { int b3 = bid - 5120; in = Wf1; out = Wf1T; R = 512;  C = 2048; gx = b3 % 64; gy = b3 / 64; }
    else                 { int b4 = bid - 6144; in = Wf2; out = Wf2T; R = 2048; C = 512;  gx = b4 % 16; gy = b4 / 16; }
    int tx = tid & 31, ty = tid >> 5;
    int c0 = gx * 32, r0 = gy * 32;
    #pragma unroll
    for (int k = 0; k < 4; ++k)
      tile[ty + k * 8][tx] = in[(size_t)(r0 + ty + k * 8) * C + c0 + tx];
    __syncthreads();
    #pragma unroll
    for (int k = 0; k < 4; ++k)
      out[(size_t)(c0 + ty + k * 8) * R + r0 + tx] = f2bf(tile[tx][ty + k * 8]);
    return;
  }
  if (bid < 7176) {
    int b = bid - 7168;
    tl[tid] = t[(size_t)b * 256 + tid];
    __syncthreads();
    float a = bt1[tid];
    for (int k = 0; k < 256; ++k) a += tl[k] * Wt1[(size_t)k * 256 + tid];
    hl[tid] = a / (1.0f + __expf(-a));
    __syncthreads();
    for (int j = tid; j < 512; j += 256) {
      float a2 = bt2[j];
      for (int k = 0; k < 256; ++k) a2 += hl[k] * Wt2[(size_t)k * 512 + j];
      tp[(size_t)b * 512 + j] = a2;
    }
    return;
  }
  int row = bid - 7176;
  const float* xr = x + (size_t)row * DIN;
  float2 v = *(const float2*)(xr + 2 * tid);
  float s = v.x + v.y, sq = v.x * v.x + v.y * v.y;
  #pragma unroll
  for (int m = 1; m < 64; m <<= 1) { s += __shfl_xor(s, m, 64); sq += __shfl_xor(sq, m, 64); }
  int w = tid >> 6;
  if ((tid & 63) == 0) { red[w] = s; red[4 + w] = sq; }
  __syncthreads();
  s  = red[0] + red[1] + red[2] + red[3];
  sq = red[4] + red[5] + red[6] + red[7];
  float mean = s * (1.0f / DIN);
  float var  = sq * (1.0f / DIN) - mean * mean;
  float rs = rsqrtf(var + 1e-5f);
  float2 gg = *(const float2*)(ln1g + 2 * tid);
  float2 bb2 = *(const float2*)(ln1b + 2 * tid);
  unsigned int o = (unsigned int)f2bf((v.x - mean) * rs * gg.x + bb2.x)
                 | ((unsigned int)f2bf((v.y - mean) * rs * gg.y + bb2.y) << 16);
  *(unsigned int*)(xn + (size_t)row * DIN + 2 * tid) = o;
}

// ---------------- LayerNorm (D=512), additive per-batch row, bf16 out -----------
__global__ __launch_bounds__(256) void ln_k(
    const float* __restrict__ x, const float* __restrict__ add,
    const float* __restrict__ g, const float* __restrict__ bb,
    unsigned short* __restrict__ out)
{
  int row = blockIdx.x;
  int tid = threadIdx.x;
  const float* xr = x + (size_t)row * DIN;
  float2 v = *(const float2*)(xr + 2 * tid);
  if (add) {
    const float* ar = add + (size_t)(row >> 10) * DIN;   // row/1024 = batch idx
    float2 a = *(const float2*)(ar + 2 * tid);
    v.x += a.x; v.y += a.y;
  }
  float s = v.x + v.y, sq = v.x * v.x + v.y * v.y;
  #pragma unroll
  for (int m = 1; m < 64; m <<= 1) { s += __shfl_xor(s, m, 64); sq += __shfl_xor(sq, m, 64); }
  __shared__ float red[8];
  int w = tid >> 6;
  if ((tid & 63) == 0) { red[w] = s; red[4 + w] = sq; }
  __syncthreads();
  s  = red[0] + red[1] + red[2] + red[3];
  sq = red[4] + red[5] + red[6] + red[7];
  float mean = s * (1.0f / DIN);
  float var  = sq * (1.0f / DIN) - mean * mean;
  float rs = rsqrtf(var + 1e-5f);
  float2 gg = *(const float2*)(g + 2 * tid);
  float2 bb2 = *(const float2*)(bb + 2 * tid);
  unsigned int o = (unsigned int)f2bf((v.x - mean) * rs * gg.x + bb2.x)
                 | ((unsigned int)f2bf((v.y - mean) * rs * gg.y + bb2.y) << 16);
  *(unsigned int*)(out + (size_t)row * DIN + 2 * tid) = o;
}

#define GSWZ(Lb, base, row, colu) \
  (*(const s16x8*)&(Lb)[(base) + (row) * 64 + (((colu) ^ (((row) & 7) * 8)))])

// ---------------- bf16 MFMA GEMM: C = epi(A @ Bt^T + bias [+res]) ---------------
// 128x128 tile, BK=64, 4 waves; double-buffered LDS, 1 barrier/k-step.
template<int EPI>
__global__ __launch_bounds__(256) void gemm_bt(
    const unsigned short* __restrict__ A, int lda,
    const unsigned short* __restrict__ Bt,
    const float* __restrict__ bias, const float* __restrict__ res,
    void* __restrict__ C, int ldc, int N, int K,
    unsigned short* __restrict__ vtout)
{
  __shared__ __attribute__((aligned(16))) unsigned short As[2 * 8192]; // 128x64 x2
  __shared__ __attribute__((aligned(16))) unsigned short Bs[2 * 8192];
  int tid = threadIdx.x;
  int m0 = blockIdx.y * 128, n0 = blockIdx.x * 128;
  int lane = tid & 63, wid = tid >> 6;
  int wr = wid >> 1, wc = wid & 1;
  int lr = lane & 15, lg = lane >> 4, lk = lg * 8;
  f32x4 zero = {0.f, 0.f, 0.f, 0.f};
  f32x4 acc[4][4];
  #pragma unroll
  for (int i = 0; i < 4; ++i)
    #pragma unroll
    for (int j = 0; j < 4; ++j) acc[i][j] = zero;
  int srow = wid * 8 + (lane >> 3);
  int scol = ((lane & 7) ^ (lane >> 3)) * 8;
  const unsigned short* gA = A  + (size_t)(m0 + srow) * lda + scol;
  const unsigned short* gB = Bt + (size_t)(n0 + srow) * K + scol;
  int nk = K >> 6;
  #pragma unroll
  for (int i = 0; i < 4; ++i) {
    gload_lds16(gA + (size_t)(i * 32) * lda, As + (i * 32 + wid * 8) * 64);
    gload_lds16(gB + (size_t)(i * 32) * K,   Bs + (i * 32 + wid * 8) * 64);
  }
  __syncthreads();
  for (int kq = 0; kq < nk; ++kq) {
    int cur = (kq & 1) * 8192;
    if (kq + 1 < nk) {
      int nxt = ((kq + 1) & 1) * 8192;
      int kt = (kq + 1) * 64;
      #pragma unroll
      for (int i = 0; i < 4; ++i) {
        gload_lds16(gA + (size_t)(i * 32) * lda + kt, As + nxt + (i * 32 + wid * 8) * 64);
        gload_lds16(gB + (size_t)(i * 32) * K   + kt, Bs + nxt + (i * 32 + wid * 8) * 64);
      }
    }
    s16x8 af[4][2], bf[4][2];
    #pragma unroll
    for (int mf = 0; mf < 4; ++mf) {
      int row = wr * 64 + mf * 16 + lr;
      af[mf][0] = GSWZ(As, cur, row, lk);
      af[mf][1] = GSWZ(As, cur, row, 32 + lk);
    }
    #pragma unroll
    for (int nf = 0; nf < 4; ++nf) {
      int row = wc * 64 + nf * 16 + lr;
      bf[nf][0] = GSWZ(Bs, cur, row, lk);
      bf[nf][1] = GSWZ(Bs, cur, row, 32 + lk);
    }
    #pragma unroll
    for (int mf = 0; mf < 4; ++mf)
      #pragma unroll
      for (int nf = 0; nf < 4; ++nf) {
        acc[mf][nf] = __builtin_amdgcn_mfma_f32_16x16x32_bf16(af[mf][0], bf[nf][0], acc[mf][nf], 0, 0, 0);
        acc[mf][nf] = __builtin_amdgcn_mfma_f32_16x16x32_bf16(af[mf][1], bf[nf][1], acc[mf][nf], 0, 0, 0);
      }
    __syncthreads();
  }
  if (EPI == 3 && n0 >= 2048) {
    #pragma unroll
    for (int mf = 0; mf < 4; ++mf) {
      int row = m0 + wr * 64 + mf * 16 + lg * 4;
      int bb = row >> 10, nn = row & 1023;
      #pragma unroll
      for (int nf = 0; nf < 4; ++nf) {
        int col = n0 + wc * 64 + nf * 16 + lr;
        float bcol = bias[col];
        int hc = col - 2048;
        int hh = hc >> 9, cc = hc & 511;
        unsigned short pk[4];
        #pragma unroll
        for (int r = 0; r < 4; ++r) pk[r] = f2bf(acc[mf][nf][r] + bcol);
        *(s16x4*)(vtout + ((size_t)((bb * 8 + hh) * 512 + cc)) * 1024 + nn) = *(const s16x4*)pk;
      }
    }
    return;
  }
  #pragma unroll
  for (int mf = 0; mf < 4; ++mf)
    #pragma unroll
    for (int nf = 0; nf < 4; ++nf) {
      int col = n0 + wc * 64 + nf * 16 + lr;
      float bcol = bias[col];
      #pragma unroll
      for (int r = 0; r < 4; ++r) {
        int row = m0 + wr * 64 + mf * 16 + lg * 4 + r;
        float v = acc[mf][nf][r] + bcol;
        if (EPI == 1) v = v / (1.0f + __expf(-v));            // swish
        if (EPI == 2) {
          v += res[(size_t)row * N + col];
          ((float*)C)[(size_t)row * ldc + col] = v;
        } else {
          ((unsigned short*)C)[(size_t)row * ldc + col] = f2bf(v);
        }
      }
    }
}

// ---------------- 64x128 GEMM (bias + f32 residual) for N=512 K-heavy shapes ----
__global__ __launch_bounds__(256) void gemm_bt64(
    const unsigned short* __restrict__ A, int lda,
    const unsigned short* __restrict__ Bt,
    const float* __restrict__ bias, const float* __restrict__ res,
    float* __restrict__ C, int ldc, int N, int K)
{
  __shared__ __attribute__((aligned(16))) unsigned short As[2 * 4096]; // 64x64 x2
  __shared__ __attribute__((aligned(16))) unsigned short Bs[2 * 8192]; // 128x64 x2
  int tid = threadIdx.x;
  int m0 = blockIdx.y * 64, n0 = blockIdx.x * 128;
  int lane = tid & 63, wid = tid >> 6;
  int lr = lane & 15, lg = lane >> 4, lk = lg * 8;
  f32x4 zero = {0.f, 0.f, 0.f, 0.f};
  f32x4 acc[4][2];
  #pragma unroll
  for (int i = 0; i < 4; ++i) { acc[i][0] = zero; acc[i][1] = zero; }
  int srow = wid * 8 + (lane >> 3);          // 0..31
  int scol = ((lane & 7) ^ (lane >> 3)) * 8;
  const unsigned short* gA = A  + (size_t)(m0 + srow) * lda + scol;
  const unsigned short* gB = Bt + (size_t)(n0 + srow) * K + scol;
  int nk = K >> 6;
  #pragma unroll
  for (int i = 0; i < 2; ++i)
    gload_lds16(gA + (size_t)(i * 32) * lda, As + (i * 32 + wid * 8) * 64);
  #pragma unroll
  for (int i = 0; i < 4; ++i)
    gload_lds16(gB + (size_t)(i * 32) * K, Bs + (i * 32 + wid * 8) * 64);
  __syncthreads();
  for (int kq = 0; kq < nk; ++kq) {
    int curA = (kq & 1) * 4096;
    int curB = (kq & 1) * 8192;
    if (kq + 1 < nk) {
      int nxtA = ((kq + 1) & 1) * 4096;
      int nxtB = ((kq + 1) & 1) * 8192;
      int kt = (kq + 1) * 64;
      #pragma unroll
      for (int i = 0; i < 2; ++i)
        gload_lds16(gA + (size_t)(i * 32) * lda + kt, As + nxtA + (i * 32 + wid * 8) * 64);
      #pragma unroll
      for (int i = 0; i < 4; ++i)
        gload_lds16(gB + (size_t)(i * 32) * K + kt, Bs + nxtB + (i * 32 + wid * 8) * 64);
    }
    s16x8 af[4][2], bf[2][2];
    #pragma unroll
    for (int mf = 0; mf < 4; ++mf) {
      int row = mf * 16 + lr;
      af[mf][0] = GSWZ(As, curA, row, lk);
      af[mf][1] = GSWZ(As, curA, row, 32 + lk);
    }
    #pragma unroll
    for (int nf = 0; nf < 2; ++nf) {
      int row = wid * 32 + nf * 16 + lr;
      bf[nf][0] = GSWZ(Bs, curB, row, lk);
      bf[nf][1] = GSWZ(Bs, curB, row, 32 + lk);
    }
    #pragma unroll
    for (int mf = 0; mf < 4; ++mf)
      #pragma unroll
      for (int nf = 0; nf < 2; ++nf) {
        acc[mf][nf] = __builtin_amdgcn_mfma_f32_16x16x32_bf16(af[mf][0], bf[nf][0], acc[mf][nf], 0, 0, 0);
        acc[mf][nf] = __builtin_amdgcn_mfma_f32_16x16x32_bf16(af[mf][1], bf[nf][1], acc[mf][nf], 0, 0, 0);
      }
    __syncthreads();
  }
  #pragma unroll
  for (int mf = 0; mf < 4; ++mf)
    #pragma unroll
    for (int nf = 0; nf < 2; ++nf) {
      int col = n0 + wid * 32 + nf * 16 + lr;
      float bcol = bias[col];
      #pragma unroll
      for (int r = 0; r < 4; ++r) {
        int row = m0 + mf * 16 + lg * 4 + r;
        C[(size_t)row * ldc + col] = acc[mf][nf][r] + bcol + res[(size_t)row * N + col];
      }
    }
}

// ---------------- fused differential attention, QBLK=128 (P stride 72) ----------
__global__ __launch_bounds__(512) void attn_k(
    const unsigned short* __restrict__ qkv, const unsigned short* __restrict__ vt,
    const float* __restrict__ lamp, unsigned short* __restrict__ aout /* = qkv+2048 */)
{
  const float scale = 0.125f;
  // pass1 overlay: KA[128][128]@0, KB@16384 (64KB). pass2: Kb0@0, Kb1@8192,
  // P dbuf @16384 (2 x 128x72 u16 = 36864B). total 69632B.
  __shared__ __attribute__((aligned(16))) unsigned short KP[34816];
  int w0 = blockIdx.x;
  int bx = (w0 & 7) * 64 + (w0 >> 3);         // 512 blocks, bijective XCD swizzle
  int bh = bx >> 3, qt = bx & 7;
  int b = bh >> 3, h = bh & 7;
  int tid = threadIdx.x;
  int lane = tid & 63, w = tid >> 6;
  int lr = lane & 15, lg = lane >> 4, lk = lg * 8;
  int qc1 = h * 64, qc2 = 512 + h * 64, kc1 = 1024 + h * 64, kc2 = 1536 + h * 64;
  f32x4 zero = {0.f, 0.f, 0.f, 0.f};
  const unsigned short* kvbase = qkv + (size_t)(b * N_) * DQKV;

  int srw = lane >> 4;                        // 0..3
  int ci0 = (lane & 15) ^ srw;
  int ci1 = (lane & 15) ^ (4 + srw);
  int scol0 = (ci0 < 8) ? (kc1 + ci0 * 8) : (kc2 + (ci0 - 8) * 8);
  int scol1 = (ci1 < 8) ? (kc1 + ci1 * 8) : (kc2 + (ci1 - 8) * 8);

  s16x8 q1f[2], q2f[2];
  {
    size_t ro = (size_t)(b * N_ + qt * 128 + w * 16 + lr) * DQKV;
    q1f[0] = *(const s16x8*)(qkv + ro + qc1 + lk);
    q1f[1] = *(const s16x8*)(qkv + ro + qc1 + 32 + lk);
    q2f[0] = *(const s16x8*)(qkv + ro + qc2 + lk);
    q2f[1] = *(const s16x8*)(qkv + ro + qc2 + 32 + lk);
  }

#define STAGE_K(Lb, kt)                                                              \
  do {                                                                               \
    gload_lds16(kvbase + (size_t)((kt) * 64 + w * 8 + srw) * DQKV + scol0,           \
                (Lb) + (w * 8) * 128);                                               \
    gload_lds16(kvbase + (size_t)((kt) * 64 + w * 8 + 4 + srw) * DQKV + scol1,       \
                (Lb) + (w * 8 + 4) * 128);                                           \
  } while (0)

#define STAGE_K128(Lb, kt)                                                           \
  do {                                                                               \
    gload_lds16(kvbase + (size_t)((kt) * 128 + w * 16 + srw) * DQKV + scol0,         \
                (Lb) + (w * 16) * 128);                                              \
    gload_lds16(kvbase + (size_t)((kt) * 128 + w * 16 + 4 + srw) * DQKV + scol1,     \
                (Lb) + (w * 16 + 4) * 128);                                          \
    gload_lds16(kvbase + (size_t)((kt) * 128 + w * 16 + 8 + srw) * DQKV + scol0,     \
                (Lb) + (w * 16 + 8) * 128);                                          \
    gload_lds16(kvbase + (size_t)((kt) * 128 + w * 16 + 12 + srw) * DQKV + scol1,    \
                (Lb) + (w * 16 + 12) * 128);                                         \
  } while (0)

#define KREAD(Lb, row, colu) (*(const s16x8*)&(Lb)[(row) * 128 + ((colu) ^ (((row) & 7) * 8))])

  unsigned short* Kb0 = KP;
  unsigned short* Kb1 = KP + 8192;
  unsigned short* Pb  = KP + 16384;
  unsigned short* KA  = KP;          // pass-1 128-row buffers (overlay)
  unsigned short* KB  = KP + 16384;

  // ---------------- pass 1: l1,l2 (KVBLK=128, 8 iters) --------------------------
  float lp1[4] = {0.f, 0.f, 0.f, 0.f}, lp2[4] = {0.f, 0.f, 0.f, 0.f};
  {
    STAGE_K128(KA, 0);
    __syncthreads();
    for (int kt = 0; kt < 8; ++kt) {
      unsigned short* Lb = (kt & 1) ? KB : KA;
      STAGE_K128((kt & 1) ? KA : KB, (kt + 1) & 7);  // wraps: re-warms KA w/ tile 0
      f32x4 s1[8], s2[8];
      #pragma unroll
      for (int nf = 0; nf < 8; ++nf) {
        int row = nf * 16 + lr;
        s16x8 a0 = KREAD(Lb, row, lk);
        s16x8 a1 = KREAD(Lb, row, 32 + lk);
        s16x8 b0 = KREAD(Lb, row, 64 + lk);
        s16x8 b1 = KREAD(Lb, row, 96 + lk);
        f32x4 t1 = __builtin_amdgcn_mfma_f32_16x16x32_bf16(q1f[0], a0, zero, 0, 0, 0);
        s1[nf]   = __builtin_amdgcn_mfma_f32_16x16x32_bf16(q1f[1], a1, t1, 0, 0, 0);
        f32x4 t2 = __builtin_amdgcn_mfma_f32_16x16x32_bf16(q2f[0], b0, zero, 0, 0, 0);
        s2[nf]   = __builtin_amdgcn_mfma_f32_16x16x32_bf16(q2f[1], b1, t2, 0, 0, 0);
      }
      #pragma unroll
      for (int nf = 0; nf < 8; ++nf)
        #pragma unroll
        for (int r = 0; r < 4; ++r) {
          lp1[r] += __expf(s1[nf][r] * scale);
          lp2[r] += __expf(s2[nf][r] * scale);
        }
      __syncthreads();                 // stage drained; all K reads done
    }
    #pragma unroll
    for (int r = 0; r < 4; ++r)
      #pragma unroll
      for (int d = 1; d < 16; d <<= 1) {
        lp1[r] += __shfl_xor(lp1[r], d, 64);
        lp2[r] += __shfl_xor(lp2[r], d, 64);
      }
  }
  float lam = *lamp;
  float r1v[4], r2v[4];
  #pragma unroll
  for (int r = 0; r < 4; ++r) { r1v[r] = 1.f / lp1[r]; r2v[r] = lam / lp2[r]; }

  // ---------------- pass 2: overlapped pipeline (Kb0/Kb1 resident from wrap) ----
  f32x4 O[8][4];
  #pragma unroll
  for (int mf = 0; mf < 8; ++mf)
    #pragma unroll
    for (int nf = 0; nf < 4; ++nf) O[mf][nf] = zero;

  auto qk_to_p = [&](const unsigned short* Lb, unsigned short* Pt) {
    f32x4 s1[4], s2[4];
    #pragma unroll
    for (int nf = 0; nf < 4; ++nf) {
      int row = nf * 16 + lr;
      s16x8 a0 = KREAD(Lb, row, lk);
      s16x8 a1 = KREAD(Lb, row, 32 + lk);
      s16x8 b0 = KREAD(Lb, row, 64 + lk);
      s16x8 b1 = KREAD(Lb, row, 96 + lk);
      f32x4 t1 = __builtin_amdgcn_mfma_f32_16x16x32_bf16(q1f[0], a0, zero, 0, 0, 0);
      s1[nf]   = __builtin_amdgcn_mfma_f32_16x16x32_bf16(q1f[1], a1, t1, 0, 0, 0);
      f32x4 t2 = __builtin_amdgcn_mfma_f32_16x16x32_bf16(q2f[0], b0, zero, 0, 0, 0);
      s2[nf]   = __builtin_amdgcn_mfma_f32_16x16x32_bf16(q2f[1], b1, t2, 0, 0, 0);
    }
    #pragma unroll
    for (int nf = 0; nf < 4; ++nf)
      #pragma unroll
      for (int r = 0; r < 4; ++r) {
        float p = __expf(s1[nf][r] * scale) * r1v[r]
                - __expf(s2[nf][r] * scale) * r2v[r];
        Pt[(w * 16 + lg * 4 + r) * 72 + nf * 16 + lr] = f2bf(p);
      }
  };

  // pre-iter: QK(0) -> P[0] (Kb0 = first half of KA = kv 0..63); stage K(1)
  qk_to_p(Kb0, Pb);
  STAGE_K(Kb1, 1);
  WAITV(0);
  WAITL0();
  __builtin_amdgcn_s_barrier();

  for (int kt = 0; kt < 16; ++kt) {
    unsigned short* Pcur = Pb + (kt & 1) * 9216;
    unsigned short* Pnxt = Pb + ((kt + 1) & 1) * 9216;
    unsigned short* Knxt = ((kt + 1) & 1) ? Kb1 : Kb0;
    unsigned short* Kstg = (kt & 1) ? Kb1 : Kb0;
    int staged = 0;
    if (kt + 2 < 16) { STAGE_K(Kstg, kt + 2); staged = 1; }
    s16x8 vf[4][2];
    #pragma unroll
    for (int nf = 0; nf < 4; ++nf)
      #pragma unroll
      for (int kq = 0; kq < 2; ++kq)
        vf[nf][kq] = *(const s16x8*)(vt + (size_t)(bh * 512 + w * 64 + nf * 16 + lr) * N_
                                     + kt * 64 + kq * 32 + lk);
    if (kt + 1 < 16) qk_to_p(Knxt, Pnxt);
    __builtin_amdgcn_s_setprio(1);
    #pragma unroll
    for (int mf = 0; mf < 8; ++mf) {
      s16x8 pf0 = *(const s16x8*)&Pcur[(mf * 16 + lr) * 72 + lk];
      s16x8 pf1 = *(const s16x8*)&Pcur[(mf * 16 + lr) * 72 + 32 + lk];
      #pragma unroll
      for (int nf = 0; nf < 4; ++nf) {
        O[mf][nf] = __builtin_amdgcn_mfma_f32_16x16x32_bf16(pf0, vf[nf][0], O[mf][nf], 0, 0, 0);
        O[mf][nf] = __builtin_amdgcn_mfma_f32_16x16x32_bf16(pf1, vf[nf][1], O[mf][nf], 0, 0, 0);
      }
    }
    __builtin_amdgcn_s_setprio(0);
    if (kt < 15) {
      if (staged) { WAITV(8); }
      else        { WAITV(0); }
      WAITL0();
      __builtin_amdgcn_s_barrier();
    }
  }
#undef STAGE_K
#undef STAGE_K128
#undef KREAD
  // epilogue
  #pragma unroll
  for (int mf = 0; mf < 8; ++mf)
    #pragma unroll
    for (int nf = 0; nf < 4; ++nf) {
      int col = h * 512 + w * 64 + nf * 16 + lr;
      #pragma unroll
      for (int r = 0; r < 4; ++r) {
        int row = b * N_ + qt * 128 + mf * 16 + lg * 4 + r;
        aout[(size_t)row * DQKV + col] = f2bf(O[mf][nf][r]);
      }
    }
}

// ---------------------------------- launcher ------------------------------------
extern "C" void kernel_launch(void* const* d_in, const int* in_sizes, int n_in,
                              void* d_out, int out_size, void* d_ws, size_t ws_size,
                              hipStream_t stream) {
  const float* x    = (const float*)d_in[0];
  const float* t    = (const float*)d_in[1];
  const float* ln1g = (const float*)d_in[2];
  const float* ln1b = (const float*)d_in[3];
  const float* Wqkv = (const float*)d_in[4];
  const float* bqkv = (const float*)d_in[5];
  const float* lam  = (const float*)d_in[6];
  const float* Wm   = (const float*)d_in[7];
  const float* bm   = (const float*)d_in[8];
  const float* Wt1  = (const float*)d_in[9];
  const float* bt1  = (const float*)d_in[10];
  const float* Wt2  = (const float*)d_in[11];
  const float* bt2  = (const float*)d_in[12];
  const float* lnfg = (const float*)d_in[13];
  const float* lnfb = (const float*)d_in[14];
  const float* Wf1  = (const float*)d_in[15];
  const float* bf1  = (const float*)d_in[16];
  const float* Wf2  = (const float*)d_in[17];
  const float* bf2  = (const float*)d_in[18];
  float* out = (float*)d_out;
  char* ws = (char*)d_ws;

  // workspace layout (bytes), ~209 MB total
  unsigned short* qkv   = (unsigned short*)(ws);                  // [8192][6144] bf16 (100.7MB)
  unsigned short* vt    = (unsigned short*)(ws + 100663296ull);   // [64][512][1024] bf16 (67MB)
  float*          x2    = (float*)(ws + 167772160ull);            // [8192][512] f32 (16.8MB)
  unsigned short* xn    = (unsigned short*)(ws + 184549376ull);   // [8192][512] bf16 (xn, then h)
  unsigned short* WqkvT = (unsigned short*)(ws + 193986560ull);   // [6144][512]
  unsigned short* WmT   = (unsigned short*)(ws + 200278016ull);   // [512][4096]
  unsigned short* Wf1T  = (unsigned short*)(ws + 204472320ull);   // [2048][512]
  unsigned short* Wf2T  = (unsigned short*)(ws + 206569472ull);   // [512][2048]
  float*          tp    = (float*)(ws + 208666624ull);            // [8][512]
  unsigned short* ff1s  = qkv;          // alias: qkv dead after attention
  unsigned short* aout  = qkv + 2048;   // alias: attention out over dead V region

  // prep: 4x weight transpose + time MLP + LN1, one dispatch
  prep_k<<<15368, 256, 0, stream>>>(
      Wqkv, WqkvT, Wm, WmT, Wf1, Wf1T, Wf2, Wf2T,
      t, Wt1, bt1, Wt2, bt2, tp, x, ln1g, ln1b, xn);
  // qkv GEMM (V columns written directly transposed into vt)
  gemm_bt<3><<<dim3(DQKV / 128, 8192 / 128), 256, 0, stream>>>(
      xn, DIN, WqkvT, bqkv, nullptr, qkv, DQKV, DQKV, DIN, vt);
  // fused two-pass differential attention (QBLK=128, KVBLK=128 pass 1)
  attn_k<<<512, 512, 0, stream>>>(qkv, vt, lam, aout);
  // x2 = x + attn_out @ Wm + bm  (64x128 tile: 512 blocks, 3 blocks/CU)
  gemm_bt64<<<dim3(DIN / 128, 8192 / 64), 256, 0, stream>>>(
      aout, DQKV, WmT, bm, x, x2, DIN, DIN, 4096);
  // h = LN(x2 + tp)
  ln_k<<<8192, 256, 0, stream>>>(x2, tp, lnfg, lnfb, xn);
  // ff1 = swish(h @ Wf1 + bf1)
  gemm_bt<1><<<dim3(DEXP / 128, 8192 / 128), 256, 0, stream>>>(
      xn, DIN, Wf1T, bf1, nullptr, ff1s, DEXP, DEXP, DIN, nullptr);
  // out = x2 + ff1 @ Wf2 + bf2  (64x128 tile)
  gemm_bt64<<<dim3(DIN / 128, 8192 / 64), 256, 0, stream>>>(
      ff1s, DEXP, Wf2T, bf2, x2, out, DIN, DIN, DEXP);
}